// Round 4
// baseline (90.107 us; speedup 1.0000x reference)
//
#include <hip/hip_runtime.h>
#include <math.h>

#define BB 512
#define SS 200
#define DD 64
#define VV 100000
#define NZB 2048
#define GRID (BB + NZB)

__device__ __forceinline__ float lane_bcast(float v, int l) {
    return __uint_as_float(__builtin_amdgcn_readlane(__float_as_uint(v), l));
}

__device__ __forceinline__ float gauss_pdf(float xx, float mu, float sg) {
    float z = (xx - mu) / sg;
    return expf(-0.5f * z * z - logf(sg) - 0.9189385332046727f);
}

// launch_bounds(256, 2): min 2 waves/EU -> VGPR budget up to 256/wave.
// Round-1 profile showed VGPR_Count=48 for the compute kernel: the default
// occupancy-targeted allocation forced the 64-float Wq column to be
// rematerialized (re-loaded) inside the 50-iteration score loop, making the
// kernel latency-bound. The wide budget keeps it live in registers.
__global__ __launch_bounds__(256, 2) void k_zero_compute(
    const float* __restrict__ x, const int* __restrict__ x_ids,
    const float* __restrict__ tg, const int* __restrict__ cla,
    const float* __restrict__ Wq, const float* __restrict__ bq,
    const float* __restrict__ Wk, const float* __restrict__ bk,
    const float* __restrict__ wv, const float* __restrict__ bv,
    const float* __restrict__ theta, float* __restrict__ out,
    int2* __restrict__ wslist)
{
    const int blk = blockIdx.x;
    const int tid = threadIdx.x;

    if (blk >= BB) {
        // ---- zeroing role: stream 204.8 MB of zeros ----
        float4* __restrict__ o4 = (float4*)out;
        const float4 z4 = make_float4(0.f, 0.f, 0.f, 0.f);
        const size_t total4 = (size_t)BB * VV / 4;          // 12.8M float4
        for (size_t i = (size_t)(blk - BB) * 256 + tid; i < total4;
             i += (size_t)NZB * 256)
            o4[i] = z4;
        return;
    }

    // ---- compute role (blocks 0..511 dispatch first, hide under zeroing) ----
    const int b    = blk;
    const int lane = tid & 63;
    const int wave = tid >> 6;

    __shared__ float sTh[17];
    __shared__ float sx0[DD];
    __shared__ float sKp[4][DD];
    __shared__ float sScore[SS];
    __shared__ float sRed[8];

    if (tid < 17) sTh[tid] = theta[tid];
    if (tid < DD) sx0[tid] = x[(size_t)b * SS * DD + tid];
    __syncthreads();

    // k_b partials: wave w covers j in [w*16, w*16+16); lane = output dim d
    {
        float acc = 0.f;
        #pragma unroll
        for (int jj = 0; jj < 16; ++jj) {
            int j = wave * 16 + jj;
            acc = fmaf(sx0[j], Wk[j * DD + lane], acc);
        }
        sKp[wave][lane] = acc;
    }

    // Wq column for d = lane, 16 named float4 (64 VGPRs), kept live
    const float* __restrict__ wp = Wq + lane;
#define LW(q) float4 w##q = make_float4(wp[(4*q+0)*DD], wp[(4*q+1)*DD], \
                                        wp[(4*q+2)*DD], wp[(4*q+3)*DD]);
    LW(0) LW(1) LW(2) LW(3) LW(4) LW(5) LW(6) LW(7)
    LW(8) LW(9) LW(10) LW(11) LW(12) LW(13) LW(14) LW(15)
#undef LW
    // opaque touch: forbid rematerializing these loads inside the s-loop
#define PIN(q) asm volatile("" : "+v"(w##q.x), "+v"(w##q.y), "+v"(w##q.z), "+v"(w##q.w));
    PIN(0) PIN(1) PIN(2) PIN(3) PIN(4) PIN(5) PIN(6) PIN(7)
    PIN(8) PIN(9) PIN(10) PIN(11) PIN(12) PIN(13) PIN(14) PIN(15)
#undef PIN
    const float wvl = wv[lane];
    const float bvv = bv[0];

    __syncthreads();

    const float kpl = sKp[0][lane] + sKp[1][lane] + sKp[2][lane] + sKp[3][lane]
                    + bk[lane] + bq[lane];

    // scores: one wave per sequence position s; lane = feature dim d
    const float* __restrict__ xb = x + (size_t)b * SS * DD;
    for (int s = wave; s < SS; s += 4) {
        float xs = xb[s * DD + lane];       // lane j holds x[b,s,j]
        float a0 = 0.f, a1 = 0.f, a2 = 0.f, a3 = 0.f;  // 4-way ILP
#define ST(J, C, A) A = fmaf(lane_bcast(xs, J), C, A);
        ST(0,w0.x,a0)  ST(1,w0.y,a1)  ST(2,w0.z,a2)  ST(3,w0.w,a3)
        ST(4,w1.x,a0)  ST(5,w1.y,a1)  ST(6,w1.z,a2)  ST(7,w1.w,a3)
        ST(8,w2.x,a0)  ST(9,w2.y,a1)  ST(10,w2.z,a2) ST(11,w2.w,a3)
        ST(12,w3.x,a0) ST(13,w3.y,a1) ST(14,w3.z,a2) ST(15,w3.w,a3)
        ST(16,w4.x,a0) ST(17,w4.y,a1) ST(18,w4.z,a2) ST(19,w4.w,a3)
        ST(20,w5.x,a0) ST(21,w5.y,a1) ST(22,w5.z,a2) ST(23,w5.w,a3)
        ST(24,w6.x,a0) ST(25,w6.y,a1) ST(26,w6.z,a2) ST(27,w6.w,a3)
        ST(28,w7.x,a0) ST(29,w7.y,a1) ST(30,w7.z,a2) ST(31,w7.w,a3)
        ST(32,w8.x,a0) ST(33,w8.y,a1) ST(34,w8.z,a2) ST(35,w8.w,a3)
        ST(36,w9.x,a0) ST(37,w9.y,a1) ST(38,w9.z,a2) ST(39,w9.w,a3)
        ST(40,w10.x,a0) ST(41,w10.y,a1) ST(42,w10.z,a2) ST(43,w10.w,a3)
        ST(44,w11.x,a0) ST(45,w11.y,a1) ST(46,w11.z,a2) ST(47,w11.w,a3)
        ST(48,w12.x,a0) ST(49,w12.y,a1) ST(50,w12.z,a2) ST(51,w12.w,a3)
        ST(52,w13.x,a0) ST(53,w13.y,a1) ST(54,w13.z,a2) ST(55,w13.w,a3)
        ST(56,w14.x,a0) ST(57,w14.y,a1) ST(58,w14.z,a2) ST(59,w14.w,a3)
        ST(60,w15.x,a0) ST(61,w15.y,a1) ST(62,w15.z,a2) ST(63,w15.w,a3)
#undef ST
        float acc = (a0 + a1) + (a2 + a3);
        float f = tanhf(acc + kpl);
        float v = f * wvl;
        #pragma unroll
        for (int off = 32; off > 0; off >>= 1) v += __shfl_xor(v, off);
        if (lane == 0) {
            int id = x_ids[b * SS + s];
            sScore[s] = (id == 0 || id == 1) ? -INFINITY : (v + bvv);
        }
    }
    __syncthreads();

    // block softmax over 200 scores (tid == s)
    float sc = (tid < SS) ? sScore[tid] : -INFINITY;
    float m = sc;
    #pragma unroll
    for (int off = 32; off > 0; off >>= 1) m = fmaxf(m, __shfl_xor(m, off));
    if (lane == 0) sRed[wave] = m;
    __syncthreads();
    const float M = fmaxf(fmaxf(sRed[0], sRed[1]), fmaxf(sRed[2], sRed[3]));
    float e = (tid < SS) ? expf(sc - M) : 0.f;
    float ssum = e;
    #pragma unroll
    for (int off = 32; off > 0; off >>= 1) ssum += __shfl_xor(ssum, off);
    if (lane == 0) sRed[4 + wave] = ssum;
    __syncthreads();
    const float Z = sRed[4] + sRed[5] + sRed[6] + sRed[7];

    const float wpg = sTh[6];
    int2* __restrict__ row = wslist + (size_t)b * 512;

    // repeat entries: slots [0, 200)
    if (tid < SS) {
        float val = (e > 0.f) ? (1.f - wpg) * (e / Z) : 0.f;
        row[tid] = make_int2(x_ids[b * SS + tid], __float_as_int(val));
    }
    // gap entries: slots [200, 399)
    if (tid < SS - 1) {
        float t  = tg[b * (SS - 1) + tid];
        int   c  = cla[b * (SS - 1) + tid];
        float c0 = (c == 0) ? t : 180.f;
        float c1 = (c == 1) ? t : 180.f;
        float c2 = (c == 2) ? t : 180.f;
        float g = sTh[0] * gauss_pdf(c0, sTh[7],  sTh[8])
                + sTh[1] * gauss_pdf(c1, sTh[9],  sTh[10])
                + sTh[2] * gauss_pdf(c1, sTh[11], sTh[12])
                + sTh[3] * gauss_pdf(c2, sTh[13], sTh[14])
                + sTh[4] * powf(c2, sTh[15]);
        row[SS + tid] = make_int2(x_ids[b * SS + tid + 1],
                                  __float_as_int(wpg * g));
    }
}

__global__ __launch_bounds__(256) void k_scatter(
    const int2* __restrict__ wslist, float* __restrict__ out)
{
    const int b   = blockIdx.x;
    const int tid = threadIdx.x;
    const int2* __restrict__ row = wslist + (size_t)b * 512;
    float* __restrict__ orow = out + (size_t)b * VV;
    for (int e = tid; e < 2 * SS - 1; e += 256) {
        int2 p = row[e];
        float v = __int_as_float(p.y);
        if (v != 0.f) atomicAdd(orow + p.x, v);
    }
}

extern "C" void kernel_launch(void* const* d_in, const int* in_sizes, int n_in,
                              void* d_out, int out_size, void* d_ws, size_t ws_size,
                              hipStream_t stream) {
    const float* x     = (const float*)d_in[0];
    const int*   x_ids = (const int*)d_in[1];
    const float* tgp   = (const float*)d_in[2];
    const int*   cl    = (const int*)d_in[3];
    const float* Wq    = (const float*)d_in[4];
    const float* bq    = (const float*)d_in[5];
    const float* Wk    = (const float*)d_in[6];
    const float* bk    = (const float*)d_in[7];
    const float* wv    = (const float*)d_in[8];
    const float* bv    = (const float*)d_in[9];
    const float* th    = (const float*)d_in[10];
    float* out   = (float*)d_out;
    int2*  wlist = (int2*)d_ws;   // 512 rows * 512 entries * 8 B = 2 MB

    hipLaunchKernelGGL(k_zero_compute, dim3(GRID), dim3(256), 0, stream,
                       x, x_ids, tgp, cl, Wq, bq, Wk, bk, wv, bv, th, out, wlist);
    hipLaunchKernelGGL(k_scatter, dim3(BB), dim3(256), 0, stream,
                       wlist, out);
}

// Round 5
// 65.442 us; speedup vs baseline: 1.3769x; 1.3769x over previous
//
#include <hip/hip_runtime.h>
#include <math.h>

#define BB 512
#define SS 200
#define DD 64
#define VV 100000

__device__ __forceinline__ float gauss_pdf(float xx, float mu, float sg) {
    float z = (xx - mu) / sg;
    return expf(-0.5f * z * z - logf(sg) - 0.9189385332046727f);
}

// tanh(x) = 1 - 2/(exp(2x)+1). Branch-free: exp->inf gives 1, exp->0 gives -1.
__device__ __forceinline__ float fast_tanh(float x) {
    float e = __expf(2.f * x);
    return 1.f - 2.f / (e + 1.f);
}

__global__ __launch_bounds__(256) void compute_scatter(
    const float* __restrict__ x, const int* __restrict__ x_ids,
    const float* __restrict__ tg, const int* __restrict__ cla,
    const float* __restrict__ Wq, const float* __restrict__ bq,
    const float* __restrict__ Wk, const float* __restrict__ bk,
    const float* __restrict__ wv, const float* __restrict__ bv,
    const float* __restrict__ theta, float* __restrict__ out)
{
    const int b    = blockIdx.x;
    const int tid  = threadIdx.x;
    const int lane = tid & 63;
    const int wave = tid >> 6;

    __shared__ float sWq[DD * DD];   // 16 KB, row-major [j][d]
    __shared__ float sx0[DD];
    __shared__ float sKp[4][DD];
    __shared__ float sK[DD];
    __shared__ float sWv[DD];
    __shared__ float sScore[SS];
    __shared__ float sRed[8];
    __shared__ float sTh[17];

    const float* __restrict__ xb = x + (size_t)b * SS * DD;

    // ---- this thread's x-row into 16 NAMED float4 regs (64 VGPRs) ----
    // Issued first: HBM/L3 latency hides under staging + k-partials.
    float4 xr0 = {0,0,0,0}, xr1 = {0,0,0,0}, xr2 = {0,0,0,0}, xr3 = {0,0,0,0},
           xr4 = {0,0,0,0}, xr5 = {0,0,0,0}, xr6 = {0,0,0,0}, xr7 = {0,0,0,0},
           xr8 = {0,0,0,0}, xr9 = {0,0,0,0}, xr10= {0,0,0,0}, xr11= {0,0,0,0},
           xr12= {0,0,0,0}, xr13= {0,0,0,0}, xr14= {0,0,0,0}, xr15= {0,0,0,0};
    if (tid < SS) {
        const float4* __restrict__ xp = (const float4*)(xb + tid * DD);
        xr0 = xp[0];  xr1 = xp[1];  xr2 = xp[2];  xr3 = xp[3];
        xr4 = xp[4];  xr5 = xp[5];  xr6 = xp[6];  xr7 = xp[7];
        xr8 = xp[8];  xr9 = xp[9];  xr10= xp[10]; xr11= xp[11];
        xr12= xp[12]; xr13= xp[13]; xr14= xp[14]; xr15= xp[15];
    }

    // ---- stage Wq / x0 / wv / theta ----
    {
        const float4* __restrict__ Wq4 = (const float4*)Wq;
        float4* __restrict__ sWq4 = (float4*)sWq;
        #pragma unroll
        for (int c = 0; c < 4; ++c) sWq4[tid + 256 * c] = Wq4[tid + 256 * c];
    }
    if (tid < DD) sx0[tid] = xb[tid];
    if (tid >= 64 && tid < 128) sWv[tid - 64] = wv[tid - 64];
    if (tid >= 128 && tid < 145) sTh[tid - 128] = theta[tid - 128];
    __syncthreads();

    // ---- k partials: wave w covers j in [16w, 16w+16); lane = d ----
    {
        float acc = 0.f;
        #pragma unroll
        for (int jj = 0; jj < 16; ++jj) {
            int j = wave * 16 + jj;
            acc = fmaf(sx0[j], Wk[j * DD + lane], acc);
        }
        sKp[wave][lane] = acc;
    }
    __syncthreads();
    if (tid < DD)
        sK[tid] = sKp[0][tid] + sKp[1][tid] + sKp[2][tid] + sKp[3][tid]
                + bq[tid] + bk[tid];
    __syncthreads();

    // ---- fused GEMV + tanh + wv-dot: thread t owns s = t ----
    if (tid < SS) {
        const float4* __restrict__ W4 = (const float4*)sWq; // [j][16 x float4]
        float scacc = 0.f;
        for (int g = 0; g < 16; ++g) {        // d-group: d = 4g..4g+3
            float a0 = 0.f, a1 = 0.f, a2 = 0.f, a3 = 0.f;
#define STEP(J, XJ) { float4 w = W4[(J)*16 + g]; \
    a0 = fmaf(XJ, w.x, a0); a1 = fmaf(XJ, w.y, a1); \
    a2 = fmaf(XJ, w.z, a2); a3 = fmaf(XJ, w.w, a3); }
            STEP(0, xr0.x)  STEP(1, xr0.y)  STEP(2, xr0.z)  STEP(3, xr0.w)
            STEP(4, xr1.x)  STEP(5, xr1.y)  STEP(6, xr1.z)  STEP(7, xr1.w)
            STEP(8, xr2.x)  STEP(9, xr2.y)  STEP(10,xr2.z)  STEP(11,xr2.w)
            STEP(12,xr3.x)  STEP(13,xr3.y)  STEP(14,xr3.z)  STEP(15,xr3.w)
            STEP(16,xr4.x)  STEP(17,xr4.y)  STEP(18,xr4.z)  STEP(19,xr4.w)
            STEP(20,xr5.x)  STEP(21,xr5.y)  STEP(22,xr5.z)  STEP(23,xr5.w)
            STEP(24,xr6.x)  STEP(25,xr6.y)  STEP(26,xr6.z)  STEP(27,xr6.w)
            STEP(28,xr7.x)  STEP(29,xr7.y)  STEP(30,xr7.z)  STEP(31,xr7.w)
            STEP(32,xr8.x)  STEP(33,xr8.y)  STEP(34,xr8.z)  STEP(35,xr8.w)
            STEP(36,xr9.x)  STEP(37,xr9.y)  STEP(38,xr9.z)  STEP(39,xr9.w)
            STEP(40,xr10.x) STEP(41,xr10.y) STEP(42,xr10.z) STEP(43,xr10.w)
            STEP(44,xr11.x) STEP(45,xr11.y) STEP(46,xr11.z) STEP(47,xr11.w)
            STEP(48,xr12.x) STEP(49,xr12.y) STEP(50,xr12.z) STEP(51,xr12.w)
            STEP(52,xr13.x) STEP(53,xr13.y) STEP(54,xr13.z) STEP(55,xr13.w)
            STEP(56,xr14.x) STEP(57,xr14.y) STEP(58,xr14.z) STEP(59,xr14.w)
            STEP(60,xr15.x) STEP(61,xr15.y) STEP(62,xr15.z) STEP(63,xr15.w)
#undef STEP
            const int d = 4 * g;
            scacc = fmaf(fast_tanh(a0 + sK[d+0]), sWv[d+0], scacc);
            scacc = fmaf(fast_tanh(a1 + sK[d+1]), sWv[d+1], scacc);
            scacc = fmaf(fast_tanh(a2 + sK[d+2]), sWv[d+2], scacc);
            scacc = fmaf(fast_tanh(a3 + sK[d+3]), sWv[d+3], scacc);
        }
        int id = x_ids[b * SS + tid];
        sScore[tid] = (id == 0 || id == 1) ? -INFINITY : (scacc + bv[0]);
    }
    __syncthreads();

    // ---- block softmax over 200 scores (tid == s) ----
    float sc = (tid < SS) ? sScore[tid] : -INFINITY;
    float m = sc;
    #pragma unroll
    for (int off = 32; off > 0; off >>= 1) m = fmaxf(m, __shfl_xor(m, off));
    if (lane == 0) sRed[wave] = m;
    __syncthreads();
    const float M = fmaxf(fmaxf(sRed[0], sRed[1]), fmaxf(sRed[2], sRed[3]));
    float e = (tid < SS) ? expf(sc - M) : 0.f;
    float ssum = e;
    #pragma unroll
    for (int off = 32; off > 0; off >>= 1) ssum += __shfl_xor(ssum, off);
    if (lane == 0) sRed[4 + wave] = ssum;
    __syncthreads();
    const float Z = sRed[4] + sRed[5] + sRed[6] + sRed[7];

    const float wpg = sTh[6];
    float* __restrict__ orow = out + (size_t)b * VV;

    // p_repeat scatter (out zeroed by the preceding memset graph node)
    if (tid < SS && e > 0.f) {
        int id = x_ids[b * SS + tid];
        atomicAdd(orow + id, (1.f - wpg) * (e / Z));
    }

    // p_gap scatter at ids x_ids[:, 1:]
    if (tid < SS - 1) {
        float t  = tg[b * (SS - 1) + tid];
        int   c  = cla[b * (SS - 1) + tid];
        float c0 = (c == 0) ? t : 180.f;
        float c1 = (c == 1) ? t : 180.f;
        float c2 = (c == 2) ? t : 180.f;
        float g = sTh[0] * gauss_pdf(c0, sTh[7],  sTh[8])
                + sTh[1] * gauss_pdf(c1, sTh[9],  sTh[10])
                + sTh[2] * gauss_pdf(c1, sTh[11], sTh[12])
                + sTh[3] * gauss_pdf(c2, sTh[13], sTh[14])
                + sTh[4] * powf(c2, sTh[15]);
        int id = x_ids[b * SS + tid + 1];
        atomicAdd(orow + id, wpg * g);
    }
}

extern "C" void kernel_launch(void* const* d_in, const int* in_sizes, int n_in,
                              void* d_out, int out_size, void* d_ws, size_t ws_size,
                              hipStream_t stream) {
    const float* x     = (const float*)d_in[0];
    const int*   x_ids = (const int*)d_in[1];
    const float* tgp   = (const float*)d_in[2];
    const int*   cl    = (const int*)d_in[3];
    const float* Wq    = (const float*)d_in[4];
    const float* bq    = (const float*)d_in[5];
    const float* Wk    = (const float*)d_in[6];
    const float* bk    = (const float*)d_in[7];
    const float* wv    = (const float*)d_in[8];
    const float* bv    = (const float*)d_in[9];
    const float* th    = (const float*)d_in[10];
    float* out = (float*)d_out;

    // Zero 204.8 MB via the driver's fill kernel (~7 TB/s -> ~29 us).
    hipMemsetAsync(out, 0, (size_t)out_size * sizeof(float), stream);

    hipLaunchKernelGGL(compute_scatter, dim3(BB), dim3(256), 0, stream,
                       x, x_ids, tgp, cl, Wq, bq, Wk, bk, wv, bv, th, out);
}

// Round 6
// 54.475 us; speedup vs baseline: 1.6541x; 1.2013x over previous
//
#include <hip/hip_runtime.h>
#include <math.h>

#define BB 512
#define SS 200
#define DD 64
#define VV 100000

__device__ __forceinline__ float gauss_pdf(float xx, float mu, float sg) {
    float z = (xx - mu) / sg;
    return expf(-0.5f * z * z - logf(sg) - 0.9189385332046727f);
}

// tanh(x) = 1 - 2/(exp(2x)+1). Branch-free: exp->inf gives 1, exp->0 gives -1.
__device__ __forceinline__ float fast_tanh(float x) {
    float e = __expf(2.f * x);
    return 1.f - 2.f / (e + 1.f);
}

__global__ __launch_bounds__(256) void fused_v6(
    const float* __restrict__ x, const int* __restrict__ x_ids,
    const float* __restrict__ tg, const int* __restrict__ cla,
    const float* __restrict__ Wq, const float* __restrict__ bq,
    const float* __restrict__ Wk, const float* __restrict__ bk,
    const float* __restrict__ wv, const float* __restrict__ bv,
    const float* __restrict__ theta, float* __restrict__ out)
{
    const int b    = blockIdx.x;
    const int tid  = threadIdx.x;
    const int lane = tid & 63;
    const int wave = tid >> 6;

    __shared__ float sWq[DD * DD];   // 16 KB, row-major [j][d]
    __shared__ float sx0[DD];
    __shared__ float sKp[4][DD];
    __shared__ float sK[DD];
    __shared__ float sWv[DD];
    __shared__ float sScore[SS];
    __shared__ float sRed[8];
    __shared__ float sTh[17];

    const float* __restrict__ xb = x + (size_t)b * SS * DD;

    // ---- this thread's x-row into 16 NAMED float4 regs (64 VGPRs) ----
    float4 xr0 = {0,0,0,0}, xr1 = {0,0,0,0}, xr2 = {0,0,0,0}, xr3 = {0,0,0,0},
           xr4 = {0,0,0,0}, xr5 = {0,0,0,0}, xr6 = {0,0,0,0}, xr7 = {0,0,0,0},
           xr8 = {0,0,0,0}, xr9 = {0,0,0,0}, xr10= {0,0,0,0}, xr11= {0,0,0,0},
           xr12= {0,0,0,0}, xr13= {0,0,0,0}, xr14= {0,0,0,0}, xr15= {0,0,0,0};
    if (tid < SS) {
        const float4* __restrict__ xp = (const float4*)(xb + tid * DD);
        xr0 = xp[0];  xr1 = xp[1];  xr2 = xp[2];  xr3 = xp[3];
        xr4 = xp[4];  xr5 = xp[5];  xr6 = xp[6];  xr7 = xp[7];
        xr8 = xp[8];  xr9 = xp[9];  xr10= xp[10]; xr11= xp[11];
        xr12= xp[12]; xr13= xp[13]; xr14= xp[14]; xr15= xp[15];
    }

    // ---- stage Wq / x0 / wv / theta ----
    {
        const float4* __restrict__ Wq4 = (const float4*)Wq;
        float4* __restrict__ sWq4 = (float4*)sWq;
        #pragma unroll
        for (int c = 0; c < 4; ++c) sWq4[tid + 256 * c] = Wq4[tid + 256 * c];
    }
    if (tid < DD) sx0[tid] = xb[tid];
    if (tid >= 64 && tid < 128) sWv[tid - 64] = wv[tid - 64];
    if (tid >= 128 && tid < 145) sTh[tid - 128] = theta[tid - 128];
    __syncthreads();

    // ---- k partials: wave w covers j in [16w, 16w+16); lane = d ----
    {
        float acc = 0.f;
        #pragma unroll
        for (int jj = 0; jj < 16; ++jj) {
            int j = wave * 16 + jj;
            acc = fmaf(sx0[j], Wk[j * DD + lane], acc);
        }
        sKp[wave][lane] = acc;
    }
    __syncthreads();
    if (tid < DD)
        sK[tid] = sKp[0][tid] + sKp[1][tid] + sKp[2][tid] + sKp[3][tid]
                + bq[tid] + bk[tid];
    __syncthreads();
    // ======== no more barriers until after the GEMV ========

    // ---- zero this block's own output row (25000 float4 = 400 KB) ----
    // Placed AFTER the last staging barrier: the stores drain at HBM rate
    // UNDER the ~30 us GEMV below; the pre-softmax __syncthreads (vmcnt(0)
    // drain) guarantees they are committed before this block's atomics.
    float* __restrict__ orow = out + (size_t)b * VV;
    {
        float4* __restrict__ orow4 = (float4*)orow;
        const float4 z4 = make_float4(0.f, 0.f, 0.f, 0.f);
        #pragma unroll 4
        for (int i = tid; i < VV / 4; i += 256) orow4[i] = z4;
    }

    // ---- fused GEMV + tanh + wv-dot: thread t owns s = t ----
    if (tid < SS) {
        const float4* __restrict__ W4 = (const float4*)sWq; // [j][16 x float4]
        float scacc = 0.f;
        for (int g = 0; g < 16; ++g) {        // d-group: d = 4g..4g+3
            float a0 = 0.f, a1 = 0.f, a2 = 0.f, a3 = 0.f;
#define STEP(J, XJ) { float4 w = W4[(J)*16 + g]; \
    a0 = fmaf(XJ, w.x, a0); a1 = fmaf(XJ, w.y, a1); \
    a2 = fmaf(XJ, w.z, a2); a3 = fmaf(XJ, w.w, a3); }
            STEP(0, xr0.x)  STEP(1, xr0.y)  STEP(2, xr0.z)  STEP(3, xr0.w)
            STEP(4, xr1.x)  STEP(5, xr1.y)  STEP(6, xr1.z)  STEP(7, xr1.w)
            STEP(8, xr2.x)  STEP(9, xr2.y)  STEP(10,xr2.z)  STEP(11,xr2.w)
            STEP(12,xr3.x)  STEP(13,xr3.y)  STEP(14,xr3.z)  STEP(15,xr3.w)
            STEP(16,xr4.x)  STEP(17,xr4.y)  STEP(18,xr4.z)  STEP(19,xr4.w)
            STEP(20,xr5.x)  STEP(21,xr5.y)  STEP(22,xr5.z)  STEP(23,xr5.w)
            STEP(24,xr6.x)  STEP(25,xr6.y)  STEP(26,xr6.z)  STEP(27,xr6.w)
            STEP(28,xr7.x)  STEP(29,xr7.y)  STEP(30,xr7.z)  STEP(31,xr7.w)
            STEP(32,xr8.x)  STEP(33,xr8.y)  STEP(34,xr8.z)  STEP(35,xr8.w)
            STEP(36,xr9.x)  STEP(37,xr9.y)  STEP(38,xr9.z)  STEP(39,xr9.w)
            STEP(40,xr10.x) STEP(41,xr10.y) STEP(42,xr10.z) STEP(43,xr10.w)
            STEP(44,xr11.x) STEP(45,xr11.y) STEP(46,xr11.z) STEP(47,xr11.w)
            STEP(48,xr12.x) STEP(49,xr12.y) STEP(50,xr12.z) STEP(51,xr12.w)
            STEP(52,xr13.x) STEP(53,xr13.y) STEP(54,xr13.z) STEP(55,xr13.w)
            STEP(56,xr14.x) STEP(57,xr14.y) STEP(58,xr14.z) STEP(59,xr14.w)
            STEP(60,xr15.x) STEP(61,xr15.y) STEP(62,xr15.z) STEP(63,xr15.w)
#undef STEP
            const int d = 4 * g;
            scacc = fmaf(fast_tanh(a0 + sK[d+0]), sWv[d+0], scacc);
            scacc = fmaf(fast_tanh(a1 + sK[d+1]), sWv[d+1], scacc);
            scacc = fmaf(fast_tanh(a2 + sK[d+2]), sWv[d+2], scacc);
            scacc = fmaf(fast_tanh(a3 + sK[d+3]), sWv[d+3], scacc);
        }
        int id = x_ids[b * SS + tid];
        sScore[tid] = (id == 0 || id == 1) ? -INFINITY : (scacc + bv[0]);
    }
    __syncthreads();   // scores ready AND this block's zero-stores drained

    // ---- block softmax over 200 scores (tid == s) ----
    float sc = (tid < SS) ? sScore[tid] : -INFINITY;
    float m = sc;
    #pragma unroll
    for (int off = 32; off > 0; off >>= 1) m = fmaxf(m, __shfl_xor(m, off));
    if (lane == 0) sRed[wave] = m;
    __syncthreads();
    const float M = fmaxf(fmaxf(sRed[0], sRed[1]), fmaxf(sRed[2], sRed[3]));
    float e = (tid < SS) ? expf(sc - M) : 0.f;
    float ssum = e;
    #pragma unroll
    for (int off = 32; off > 0; off >>= 1) ssum += __shfl_xor(ssum, off);
    if (lane == 0) sRed[4 + wave] = ssum;
    __syncthreads();
    const float Z = sRed[4] + sRed[5] + sRed[6] + sRed[7];

    const float wpg = sTh[6];

    // p_repeat scatter into this block's own (already-zeroed) row
    if (tid < SS && e > 0.f) {
        int id = x_ids[b * SS + tid];
        atomicAdd(orow + id, (1.f - wpg) * (e / Z));
    }

    // p_gap scatter at ids x_ids[:, 1:]
    if (tid < SS - 1) {
        float t  = tg[b * (SS - 1) + tid];
        int   c  = cla[b * (SS - 1) + tid];
        float c0 = (c == 0) ? t : 180.f;
        float c1 = (c == 1) ? t : 180.f;
        float c2 = (c == 2) ? t : 180.f;
        float g = sTh[0] * gauss_pdf(c0, sTh[7],  sTh[8])
                + sTh[1] * gauss_pdf(c1, sTh[9],  sTh[10])
                + sTh[2] * gauss_pdf(c1, sTh[11], sTh[12])
                + sTh[3] * gauss_pdf(c2, sTh[13], sTh[14])
                + sTh[4] * powf(c2, sTh[15]);
        int id = x_ids[b * SS + tid + 1];
        atomicAdd(orow + id, wpg * g);
    }
}

extern "C" void kernel_launch(void* const* d_in, const int* in_sizes, int n_in,
                              void* d_out, int out_size, void* d_ws, size_t ws_size,
                              hipStream_t stream) {
    const float* x     = (const float*)d_in[0];
    const int*   x_ids = (const int*)d_in[1];
    const float* tgp   = (const float*)d_in[2];
    const int*   cl    = (const int*)d_in[3];
    const float* Wq    = (const float*)d_in[4];
    const float* bq    = (const float*)d_in[5];
    const float* Wk    = (const float*)d_in[6];
    const float* bk    = (const float*)d_in[7];
    const float* wv    = (const float*)d_in[8];
    const float* bv    = (const float*)d_in[9];
    const float* th    = (const float*)d_in[10];
    float* out = (float*)d_out;

    hipLaunchKernelGGL(fused_v6, dim3(BB), dim3(256), 0, stream,
                       x, x_ids, tgp, cl, Wq, bq, Wk, bk, wv, bv, th, out);
}